// Round 14
// baseline (1222.104 us; speedup 1.0000x reference)
//
#include <hip/hip_runtime.h>
#include <cstdint>
#include <cstddef>

typedef __bf16 bf16x8 __attribute__((ext_vector_type(8)));
typedef float f32x4 __attribute__((ext_vector_type(4)));
typedef unsigned int u32x4 __attribute__((ext_vector_type(4)));

// float -> bf16, round-half-up (weights; proven all passing rounds)
__device__ __forceinline__ unsigned short f2bf(float f) {
  union { float f; unsigned int u; } v; v.f = f;
  return (unsigned short)((v.u + 0x8000u) >> 16);
}

// Packed f32x2 -> bf16x2 (RNE), single VALU op (passed round 13).
__device__ __forceinline__ unsigned cvtpk(float a, float b) {
  unsigned r;
  asm("v_cvt_pk_bf16_f32 %0, %1, %2" : "=v"(r) : "v"(a), "v"(b));
  return r;
}

// GELU via sigmoid identity (verified in prior rounds)
__device__ __forceinline__ float gelu_s(float x) {
  float x2 = x * x;
  float p = __builtin_fmaf(x2, -0.10294324f, -2.30220819f);
  float e = __builtin_amdgcn_exp2f(x * p);
  return x * __builtin_amdgcn_rcpf(1.0f + e);
}

// async global->LDS, 16B/lane. LDS dest is wave-uniform base + lane*16.
// (with tid*16 dest and 512 threads: base = w*1024 + lane*16 -- still
// wave-uniform base + lane*16, verified.)
#define GLOAD16(gsrc, ldst)                                                  \
  __builtin_amdgcn_global_load_lds(                                          \
      (const __attribute__((address_space(1))) unsigned int*)(gsrc),         \
      (__attribute__((address_space(3))) unsigned int*)(uintptr_t)(          \
          (char*)(ldst)),                                                    \
      16, 0, 0)

// Swizzled tile: 16B chunk (row R, col8 C in [0,8)) at
// (R>>5)*4096 + ((R&31)*8 + (C ^ (R&7)))*16.  (proven rounds 0-5/13)
#define SWZ_FRAG(base, R, C8)                                                \
  (*(const bf16x8*)((base) + (((R) >> 5) * 4096) +                           \
                    ((((R)&31) * 8 + ((C8) ^ ((R)&7))) * 16)))

// A-tile staging, 512 threads: z f32 -> cvt_pk bf16 -> swizzled LDS.
// Thread t covers rows (t>>3) + 64*it (it=0,1); dest byte it*8192 + t*16
// equals the swizzle formula for R = it*64 + (t>>3), c8d = t&7 (verified:
// t*16 = (t>>8)*4096 + ((t>>3)&31)*128 + (t&7)*16).
__device__ __forceinline__ void stage_A_512(const float* __restrict__ ag,
                                            char* lds, int tid, int ko) {
  f32x4 a0[2], a1[2];
#pragma unroll
  for (int it = 0; it < 2; ++it) {
    const float* p = ag + it * 64 * 512 + ko;
    a0[it] = *(const f32x4*)(p);
    a1[it] = *(const f32x4*)(p + 4);
  }
#pragma unroll
  for (int it = 0; it < 2; ++it) {
    u32x4 v;
    v[0] = cvtpk(a0[it][0], a0[it][1]);
    v[1] = cvtpk(a0[it][2], a0[it][3]);
    v[2] = cvtpk(a1[it][0], a1[it][1]);
    v[3] = cvtpk(a1[it][2], a1[it][3]);
    *(u32x4*)(lds + it * 8192 + tid * 16) = v;
  }
}

// ---------------------------------------------------------------------------
// Expert-PAIR tile: 128 rows x 2 experts (e0, e0+1), 8 waves.
//   wave wq: esub = wq>>2 (expert), wr = (wq>>1)&1 (row half), wc = wq&1
//   (col half). Each wave: 64x64 output = 4x4 acc of 16x16x32.
// A staged ONCE per kt for both experts (the halved-cost operand);
// B (w1t bf16) via GLOAD16, 2 experts' tiles side by side.
// ---------------------------------------------------------------------------
__device__ __forceinline__ void expert_pair_tile(
    int e0, int mbase, const float* __restrict__ z,
    const unsigned short* __restrict__ w1t, const float* __restrict__ b1,
    const float* __restrict__ w2, const float* __restrict__ b2,
    float* __restrict__ out, char* lds, int tid, int wq, int l15, int l4,
    int c8s) {
  char* ldsB = lds + 16384;
  const float* ag = z + (size_t)(mbase + (tid >> 3)) * 512 + c8s;
  const unsigned short* bg = w1t + e0 * 65536 + (tid >> 3) * 512 + c8s;
  const int esub = wq >> 2;
  const int wr = (wq >> 1) & 1;
  const int wc = wq & 1;
  char* ldsBe = ldsB + esub * 16384;
  f32x4 acc[4][4] = {};
  for (int kt = 0; kt < 8; ++kt) {
    const int ko = kt * 64;
#pragma unroll
    for (int sub = 0; sub < 2; ++sub)
#pragma unroll
      for (int it = 0; it < 2; ++it)
        GLOAD16(bg + sub * 65536 + it * 64 * 512 + ko,
                ldsB + sub * 16384 + it * 8192 + tid * 16);
    stage_A_512(ag, lds, tid, ko);
    __syncthreads();
#pragma unroll
    for (int ks = 0; ks < 2; ++ks) {
      bf16x8 af[4];
#pragma unroll
      for (int rt = 0; rt < 4; ++rt)
        af[rt] = SWZ_FRAG(lds, wr * 64 + rt * 16 + l15, ks * 4 + l4);
#pragma unroll
      for (int ct = 0; ct < 4; ++ct) {
        bf16x8 bfv = SWZ_FRAG(ldsBe, wc * 64 + ct * 16 + l15, ks * 4 + l4);
#pragma unroll
        for (int rt = 0; rt < 4; ++rt)
          acc[rt][ct] = __builtin_amdgcn_mfma_f32_16x16x32_bf16(
              af[rt], bfv, acc[rt][ct], 0, 0, 0);
      }
    }
    __syncthreads();
  }
  // epilogue: partial y over this wave's 64 cols, cross-wave combine
  const int e = e0 + esub;
  float b1v[4], w2v[4];
#pragma unroll
  for (int ct = 0; ct < 4; ++ct) {
    int n = wc * 64 + ct * 16 + l15;
    b1v[ct] = b1[e * 128 + n];
    w2v[ct] = w2[e * 128 + n];
  }
  float* ylds = (float*)(lds + 49152);  // [8 waves][64 rows]
#pragma unroll
  for (int rt = 0; rt < 4; ++rt) {
#pragma unroll
    for (int i = 0; i < 4; ++i) {
      float s = 0.0f;
#pragma unroll
      for (int ct = 0; ct < 4; ++ct)
        s += gelu_s(acc[rt][ct][i] + b1v[ct]) * w2v[ct];
#pragma unroll
      for (int off = 1; off < 16; off <<= 1) s += __shfl_xor(s, off, 16);
      if (l15 == 0) ylds[wq * 64 + rt * 16 + l4 * 4 + i] = s;
    }
  }
  __syncthreads();
  if (tid < 256) {
    int rl = tid & 63;
    int half = (tid >> 6) & 1;   // row half
    int es = tid >> 7;           // expert sub
    float y = ylds[(es * 4 + half * 2) * 64 + rl] +
              ylds[(es * 4 + half * 2 + 1) * 64 + rl] + b2[e0 + es];
    out[(size_t)2097152 + (size_t)(mbase + half * 64 + rl) * 16 + e0 + es] =
        y;
  }
}

// ---------------------------------------------------------------------------
// Logits tile, 512 threads: 8 waves x 16 rows each. Wc from wct (L2-hot).
// ---------------------------------------------------------------------------
__device__ __forceinline__ void logits_tile(
    int mbase, const float* __restrict__ z,
    const unsigned short* __restrict__ wct, const float* __restrict__ bc,
    float* __restrict__ out, char* lds, int tid, int wq, int l15, int l4,
    int c8s) {
  const float* ag = z + (size_t)(mbase + (tid >> 3)) * 512 + c8s;
  const unsigned short* wb = wct + l15 * 512 + l4 * 8;
  f32x4 acc2 = {};
  for (int kt = 0; kt < 8; ++kt) {
    const int ko = kt * 64;
    stage_A_512(ag, lds, tid, ko);
    bf16x8 bfr0 = *(const bf16x8*)(wb + ko);
    bf16x8 bfr1 = *(const bf16x8*)(wb + ko + 32);
    __syncthreads();
    bf16x8 a0 = SWZ_FRAG(lds, wq * 16 + l15, l4);
    acc2 = __builtin_amdgcn_mfma_f32_16x16x32_bf16(a0, bfr0, acc2, 0, 0, 0);
    bf16x8 a1 = SWZ_FRAG(lds, wq * 16 + l15, 4 + l4);
    acc2 = __builtin_amdgcn_mfma_f32_16x16x32_bf16(a1, bfr1, acc2, 0, 0, 0);
    __syncthreads();
  }
  float bcv = bc[l15];
#pragma unroll
  for (int i = 0; i < 4; ++i) {
    int row = wq * 16 + l4 * 4 + i;
    float lg = acc2[i] + bcv;
    float mx = lg;
#pragma unroll
    for (int off = 1; off < 16; off <<= 1)
      mx = fmaxf(mx, __shfl_xor(mx, off, 16));
    float ex = __expf(lg - mx);
    float sm = ex;
#pragma unroll
    for (int off = 1; off < 16; off <<= 1) sm += __shfl_xor(sm, off, 16);
    size_t ro = (size_t)(mbase + row) * 16 + l15;
    out[ro] = lg;                 // logits
    out[1048576 + ro] = ex / sm;  // p_g
  }
}

// ---------------------------------------------------------------------------
// Weight conversion (round-5 proven, ~8us):
//   bid < 1024 : W1[g,d,h] -> W1t[g,h,d] bf16 via 32x32 LDS tile
//   bid == 1024: Wc[d,g] -> Wct[g,d] bf16
// ---------------------------------------------------------------------------
__global__ __launch_bounds__(256) void k_convert(
    const float* __restrict__ W1, const float* __restrict__ Wc,
    unsigned short* __restrict__ w1t, unsigned short* __restrict__ wct) {
  int bid = blockIdx.x;
  int tid = threadIdx.x;
  if (bid < 1024) {
    __shared__ float tile[32][33];
    int gg = bid >> 6;
    int t = bid & 63;
    int d0 = (t >> 2) * 32;
    int h0 = (t & 3) * 32;
    int tx = tid & 31, ty = tid >> 5;
#pragma unroll
    for (int r = 0; r < 4; ++r)
      tile[r * 8 + ty][tx] = W1[(gg << 16) + (d0 + r * 8 + ty) * 128 + h0 + tx];
    __syncthreads();
#pragma unroll
    for (int r = 0; r < 4; ++r)
      w1t[(gg << 16) + (h0 + r * 8 + ty) * 512 + d0 + tx] =
          f2bf(tile[tx][r * 8 + ty]);
  } else {
#pragma unroll
    for (int j = 0; j < 32; ++j) {
      int i = j * 256 + tid;
      wct[(i & 15) * 512 + (i >> 4)] = f2bf(Wc[i]);
    }
  }
}

// ---------------------------------------------------------------------------
// Main kernel: 4608 blocks x 512 threads = 8 XCDs x 64 panels x 9 tiles
//   (1 logits + 8 expert-pair). xcd = bid&7, t = bid>>3, panel = xcd*64+t/9,
//   r = t%9: r==0 -> logits; else expert pair e0 = (r-1)*2.
// LDS: A 16K | B 32K (2 experts) | ylds 2K = 50K -> 3 blocks/CU, 24 w/CU.
// ---------------------------------------------------------------------------
__global__ __launch_bounds__(512, 6) void k_main(
    const float* __restrict__ z, const unsigned short* __restrict__ w1t,
    const unsigned short* __restrict__ wct, const float* __restrict__ bc,
    const float* __restrict__ b1, const float* __restrict__ w2,
    const float* __restrict__ b2, float* __restrict__ out) {
  __shared__ alignas(16) char lds[16384 + 32768 + 2048];
  const int tid = threadIdx.x;
  const int wq = tid >> 6;
  const int l15 = tid & 15;
  const int l4 = (tid >> 4) & 3;
  const int c8s = (((tid & 7) ^ ((tid >> 3) & 7))) * 8;
  const int xcd = blockIdx.x & 7;
  const int t = blockIdx.x >> 3;  // 0..575
  const int pl = t / 9;           // panel-local 0..63
  const int r = t - pl * 9;       // 0..8
  const int mbase = (xcd * 64 + pl) * 128;
  if (r == 0)
    logits_tile(mbase, z, wct, bc, out, lds, tid, wq, l15, l4, c8s);
  else
    expert_pair_tile((r - 1) * 2, mbase, z, w1t, b1, w2, b2, out, lds, tid,
                     wq, l15, l4, c8s);
}

// ---------------------------------------------------------------------------
extern "C" void kernel_launch(void* const* d_in, const int* in_sizes, int n_in,
                              void* d_out, int out_size, void* d_ws,
                              size_t ws_size, hipStream_t stream) {
  const float* z = (const float*)d_in[0];
  const float* Wc = (const float*)d_in[1];
  const float* bc = (const float*)d_in[2];
  const float* W1 = (const float*)d_in[3];
  const float* b1 = (const float*)d_in[4];
  const float* W2 = (const float*)d_in[5];
  const float* b2 = (const float*)d_in[6];
  float* out = (float*)d_out;

  unsigned short* w1t = (unsigned short*)d_ws;           // 2 MB
  unsigned short* wct = w1t + (size_t)16 * 128 * 512;    // 16 KB

  k_convert<<<1024 + 1, 256, 0, stream>>>(W1, Wc, w1t, wct);
  k_main<<<8 * 576, 512, 0, stream>>>(z, w1t, wct, bc, b1, W2, b2, out);
}

// Round 15
// 367.252 us; speedup vs baseline: 3.3277x; 3.3277x over previous
//
#include <hip/hip_runtime.h>
#include <cstdint>
#include <cstddef>

typedef __bf16 bf16x8 __attribute__((ext_vector_type(8)));
typedef float f32x4 __attribute__((ext_vector_type(4)));
typedef unsigned int u32x4 __attribute__((ext_vector_type(4)));

// float -> bf16, round-half-up (weights; proven all passing rounds)
__device__ __forceinline__ unsigned short f2bf(float f) {
  union { float f; unsigned int u; } v; v.f = f;
  return (unsigned short)((v.u + 0x8000u) >> 16);
}

// Packed f32x2 -> bf16x2 (RNE), single VALU op (passed rounds 13/14).
__device__ __forceinline__ unsigned cvtpk(float a, float b) {
  unsigned r;
  asm("v_cvt_pk_bf16_f32 %0, %1, %2" : "=v"(r) : "v"(a), "v"(b));
  return r;
}

// GELU via sigmoid identity (verified in prior rounds)
__device__ __forceinline__ float gelu_s(float x) {
  float x2 = x * x;
  float p = __builtin_fmaf(x2, -0.10294324f, -2.30220819f);
  float e = __builtin_amdgcn_exp2f(x * p);
  return x * __builtin_amdgcn_rcpf(1.0f + e);
}

// async global->LDS, 16B/lane. LDS dest is wave-uniform base + lane*16.
#define GLOAD16(gsrc, ldst)                                                  \
  __builtin_amdgcn_global_load_lds(                                          \
      (const __attribute__((address_space(1))) unsigned int*)(gsrc),         \
      (__attribute__((address_space(3))) unsigned int*)(uintptr_t)(          \
          (char*)(ldst)),                                                    \
      16, 0, 0)

// Swizzled tile: 16B chunk (row R, col8 C in [0,8)) at
// (R>>5)*4096 + ((R&31)*8 + (C ^ (R&7)))*16.  (proven rounds 0-5/13/14)
#define SWZ_FRAG(base, R, C8)                                                \
  (*(const bf16x8*)((base) + (((R) >> 5) * 4096) +                           \
                    ((((R)&31) * 8 + ((C8) ^ ((R)&7))) * 16)))

// A-tile staging, 512 threads: z f32 -> cvt_pk bf16 -> swizzled LDS.
// (correctness proven round 14)
__device__ __forceinline__ void stage_A_512(const float* __restrict__ ag,
                                            char* lds, int tid, int ko) {
  f32x4 a0[2], a1[2];
#pragma unroll
  for (int it = 0; it < 2; ++it) {
    const float* p = ag + it * 64 * 512 + ko;
    a0[it] = *(const f32x4*)(p);
    a1[it] = *(const f32x4*)(p + 4);
  }
#pragma unroll
  for (int it = 0; it < 2; ++it) {
    u32x4 v;
    v[0] = cvtpk(a0[it][0], a0[it][1]);
    v[1] = cvtpk(a0[it][2], a0[it][3]);
    v[2] = cvtpk(a1[it][0], a1[it][1]);
    v[3] = cvtpk(a1[it][2], a1[it][3]);
    *(u32x4*)(lds + it * 8192 + tid * 16) = v;
  }
}

// ---------------------------------------------------------------------------
// Expert-PAIR tile: 128 rows x 2 experts, 8 waves (proven correct round 14).
// ---------------------------------------------------------------------------
__device__ __forceinline__ void expert_pair_tile(
    int e0, int mbase, const float* __restrict__ z,
    const unsigned short* __restrict__ w1t, const float* __restrict__ b1,
    const float* __restrict__ w2, const float* __restrict__ b2,
    float* __restrict__ out, char* lds, int tid, int wq, int l15, int l4,
    int c8s) {
  char* ldsB = lds + 16384;
  const float* ag = z + (size_t)(mbase + (tid >> 3)) * 512 + c8s;
  const unsigned short* bg = w1t + e0 * 65536 + (tid >> 3) * 512 + c8s;
  const int esub = wq >> 2;
  const int wr = (wq >> 1) & 1;
  const int wc = wq & 1;
  char* ldsBe = ldsB + esub * 16384;
  f32x4 acc[4][4] = {};
  for (int kt = 0; kt < 8; ++kt) {
    const int ko = kt * 64;
#pragma unroll
    for (int sub = 0; sub < 2; ++sub)
#pragma unroll
      for (int it = 0; it < 2; ++it)
        GLOAD16(bg + sub * 65536 + it * 64 * 512 + ko,
                ldsB + sub * 16384 + it * 8192 + tid * 16);
    stage_A_512(ag, lds, tid, ko);
    __syncthreads();
#pragma unroll
    for (int ks = 0; ks < 2; ++ks) {
      bf16x8 af[4];
#pragma unroll
      for (int rt = 0; rt < 4; ++rt)
        af[rt] = SWZ_FRAG(lds, wr * 64 + rt * 16 + l15, ks * 4 + l4);
#pragma unroll
      for (int ct = 0; ct < 4; ++ct) {
        bf16x8 bfv = SWZ_FRAG(ldsBe, wc * 64 + ct * 16 + l15, ks * 4 + l4);
#pragma unroll
        for (int rt = 0; rt < 4; ++rt)
          acc[rt][ct] = __builtin_amdgcn_mfma_f32_16x16x32_bf16(
              af[rt], bfv, acc[rt][ct], 0, 0, 0);
      }
    }
    __syncthreads();
  }
  // epilogue: partial y over this wave's 64 cols, cross-wave combine
  const int e = e0 + esub;
  float b1v[4], w2v[4];
#pragma unroll
  for (int ct = 0; ct < 4; ++ct) {
    int n = wc * 64 + ct * 16 + l15;
    b1v[ct] = b1[e * 128 + n];
    w2v[ct] = w2[e * 128 + n];
  }
  float* ylds = (float*)(lds + 49152);  // [8 waves][64 rows]
#pragma unroll
  for (int rt = 0; rt < 4; ++rt) {
#pragma unroll
    for (int i = 0; i < 4; ++i) {
      float s = 0.0f;
#pragma unroll
      for (int ct = 0; ct < 4; ++ct)
        s += gelu_s(acc[rt][ct][i] + b1v[ct]) * w2v[ct];
#pragma unroll
      for (int off = 1; off < 16; off <<= 1) s += __shfl_xor(s, off, 16);
      if (l15 == 0) ylds[wq * 64 + rt * 16 + l4 * 4 + i] = s;
    }
  }
  __syncthreads();
  if (tid < 256) {
    int rl = tid & 63;
    int half = (tid >> 6) & 1;   // row half
    int es = tid >> 7;           // expert sub
    float y = ylds[(es * 4 + half * 2) * 64 + rl] +
              ylds[(es * 4 + half * 2 + 1) * 64 + rl] + b2[e0 + es];
    out[(size_t)2097152 + (size_t)(mbase + half * 64 + rl) * 16 + e0 + es] =
        y;
  }
}

// ---------------------------------------------------------------------------
// Logits tile, 512 threads (proven correct round 14).
// ---------------------------------------------------------------------------
__device__ __forceinline__ void logits_tile(
    int mbase, const float* __restrict__ z,
    const unsigned short* __restrict__ wct, const float* __restrict__ bc,
    float* __restrict__ out, char* lds, int tid, int wq, int l15, int l4,
    int c8s) {
  const float* ag = z + (size_t)(mbase + (tid >> 3)) * 512 + c8s;
  const unsigned short* wb = wct + l15 * 512 + l4 * 8;
  f32x4 acc2 = {};
  for (int kt = 0; kt < 8; ++kt) {
    const int ko = kt * 64;
    stage_A_512(ag, lds, tid, ko);
    bf16x8 bfr0 = *(const bf16x8*)(wb + ko);
    bf16x8 bfr1 = *(const bf16x8*)(wb + ko + 32);
    __syncthreads();
    bf16x8 a0 = SWZ_FRAG(lds, wq * 16 + l15, l4);
    acc2 = __builtin_amdgcn_mfma_f32_16x16x32_bf16(a0, bfr0, acc2, 0, 0, 0);
    bf16x8 a1 = SWZ_FRAG(lds, wq * 16 + l15, 4 + l4);
    acc2 = __builtin_amdgcn_mfma_f32_16x16x32_bf16(a1, bfr1, acc2, 0, 0, 0);
    __syncthreads();
  }
  float bcv = bc[l15];
#pragma unroll
  for (int i = 0; i < 4; ++i) {
    int row = wq * 16 + l4 * 4 + i;
    float lg = acc2[i] + bcv;
    float mx = lg;
#pragma unroll
    for (int off = 1; off < 16; off <<= 1)
      mx = fmaxf(mx, __shfl_xor(mx, off, 16));
    float ex = __expf(lg - mx);
    float sm = ex;
#pragma unroll
    for (int off = 1; off < 16; off <<= 1) sm += __shfl_xor(sm, off, 16);
    size_t ro = (size_t)(mbase + row) * 16 + l15;
    out[ro] = lg;                 // logits
    out[1048576 + ro] = ex / sm;  // p_g
  }
}

// ---------------------------------------------------------------------------
// Weight conversion (round-5 proven, ~8us).
// ---------------------------------------------------------------------------
__global__ __launch_bounds__(256) void k_convert(
    const float* __restrict__ W1, const float* __restrict__ Wc,
    unsigned short* __restrict__ w1t, unsigned short* __restrict__ wct) {
  int bid = blockIdx.x;
  int tid = threadIdx.x;
  if (bid < 1024) {
    __shared__ float tile[32][33];
    int gg = bid >> 6;
    int t = bid & 63;
    int d0 = (t >> 2) * 32;
    int h0 = (t & 3) * 32;
    int tx = tid & 31, ty = tid >> 5;
#pragma unroll
    for (int r = 0; r < 4; ++r)
      tile[r * 8 + ty][tx] = W1[(gg << 16) + (d0 + r * 8 + ty) * 128 + h0 + tx];
    __syncthreads();
#pragma unroll
    for (int r = 0; r < 4; ++r)
      w1t[(gg << 16) + (h0 + r * 8 + ty) * 512 + d0 + tx] =
          f2bf(tile[tx][r * 8 + ty]);
  } else {
#pragma unroll
    for (int j = 0; j < 32; ++j) {
      int i = j * 256 + tid;
      wct[(i & 15) * 512 + (i >> 4)] = f2bf(Wc[i]);
    }
  }
}

// ---------------------------------------------------------------------------
// Main kernel: 4608 blocks x 512 threads = 8 XCDs x 64 panels x 9 tiles.
// __launch_bounds__(512, 4): 4 waves/EU -> 128 regs/wave (fits 64 AGPR acc
// + ~40 VGPR, NO SPILL — round 14's (512,6) capped at 85 and spilled acc to
// scratch: 5GB HBM traffic, 1090us). 2 blocks/CU (LDS 100K), 16 waves/CU.
// ---------------------------------------------------------------------------
__global__ __launch_bounds__(512, 4) void k_main(
    const float* __restrict__ z, const unsigned short* __restrict__ w1t,
    const unsigned short* __restrict__ wct, const float* __restrict__ bc,
    const float* __restrict__ b1, const float* __restrict__ w2,
    const float* __restrict__ b2, float* __restrict__ out) {
  __shared__ alignas(16) char lds[16384 + 32768 + 2048];
  const int tid = threadIdx.x;
  const int wq = tid >> 6;
  const int l15 = tid & 15;
  const int l4 = (tid >> 4) & 3;
  const int c8s = (((tid & 7) ^ ((tid >> 3) & 7))) * 8;
  const int xcd = blockIdx.x & 7;
  const int t = blockIdx.x >> 3;  // 0..575
  const int pl = t / 9;           // panel-local 0..63
  const int r = t - pl * 9;       // 0..8
  const int mbase = (xcd * 64 + pl) * 128;
  if (r == 0)
    logits_tile(mbase, z, wct, bc, out, lds, tid, wq, l15, l4, c8s);
  else
    expert_pair_tile((r - 1) * 2, mbase, z, w1t, b1, w2, b2, out, lds, tid,
                     wq, l15, l4, c8s);
}

// ---------------------------------------------------------------------------
extern "C" void kernel_launch(void* const* d_in, const int* in_sizes, int n_in,
                              void* d_out, int out_size, void* d_ws,
                              size_t ws_size, hipStream_t stream) {
  const float* z = (const float*)d_in[0];
  const float* Wc = (const float*)d_in[1];
  const float* bc = (const float*)d_in[2];
  const float* W1 = (const float*)d_in[3];
  const float* b1 = (const float*)d_in[4];
  const float* W2 = (const float*)d_in[5];
  const float* b2 = (const float*)d_in[6];
  float* out = (float*)d_out;

  unsigned short* w1t = (unsigned short*)d_ws;           // 2 MB
  unsigned short* wct = w1t + (size_t)16 * 128 * 512;    // 16 KB

  k_convert<<<1024 + 1, 256, 0, stream>>>(W1, Wc, w1t, wct);
  k_main<<<8 * 576, 512, 0, stream>>>(z, w1t, wct, bc, b1, W2, b2, out);
}

// Round 17
// 365.613 us; speedup vs baseline: 3.3426x; 1.0045x over previous
//
#include <hip/hip_runtime.h>
#include <cstdint>
#include <cstddef>

typedef __bf16 bf16x8 __attribute__((ext_vector_type(8)));
typedef float f32x4 __attribute__((ext_vector_type(4)));
typedef unsigned int u32x4 __attribute__((ext_vector_type(4)));

// float -> bf16, round-half-up (weights; proven all passing rounds)
__device__ __forceinline__ unsigned short f2bf(float f) {
  union { float f; unsigned int u; } v; v.f = f;
  return (unsigned short)((v.u + 0x8000u) >> 16);
}

// Packed f32x2 -> bf16x2 (RNE), single VALU op (passed rounds 13-15).
__device__ __forceinline__ unsigned cvtpk(float a, float b) {
  unsigned r;
  asm("v_cvt_pk_bf16_f32 %0, %1, %2" : "=v"(r) : "v"(a), "v"(b));
  return r;
}

// GELU via sigmoid identity (verified in prior rounds)
__device__ __forceinline__ float gelu_s(float x) {
  float x2 = x * x;
  float p = __builtin_fmaf(x2, -0.10294324f, -2.30220819f);
  float e = __builtin_amdgcn_exp2f(x * p);
  return x * __builtin_amdgcn_rcpf(1.0f + e);
}

// async global->LDS, 16B/lane. LDS dest is wave-uniform base + lane*16.
#define GLOAD16(gsrc, ldst)                                                  \
  __builtin_amdgcn_global_load_lds(                                          \
      (const __attribute__((address_space(1))) unsigned int*)(gsrc),         \
      (__attribute__((address_space(3))) unsigned int*)(uintptr_t)(          \
          (char*)(ldst)),                                                    \
      16, 0, 0)

// Swizzled tile: 16B chunk (row R, col8 C in [0,8)) at
// (R>>5)*4096 + ((R&31)*8 + (C ^ (R&7)))*16.  (proven rounds 0-5/13)
#define SWZ_FRAG(base, R, C8)                                                \
  (*(const bf16x8*)((base) + (((R) >> 5) * 4096) +                           \
                    ((((R)&31) * 8 + ((C8) ^ ((R)&7))) * 16)))

// --- T14 split A-staging (r13's stage_A_f32 = load_A immediately followed
// --- by write_A; here the issue is hoisted to fly under the MFMA phase). ---
__device__ __forceinline__ void load_A(const float* __restrict__ ag, int ko,
                                       f32x4* a0, f32x4* a1) {
#pragma unroll
  for (int it = 0; it < 4; ++it) {
    const float* p = ag + it * 32 * 512 + ko;
    a0[it] = *(const f32x4*)(p);
    a1[it] = *(const f32x4*)(p + 4);
  }
}
__device__ __forceinline__ void write_A(char* lds, int tid, const f32x4* a0,
                                        const f32x4* a1) {
#pragma unroll
  for (int it = 0; it < 4; ++it) {
    u32x4 v;
    v[0] = cvtpk(a0[it][0], a0[it][1]);
    v[1] = cvtpk(a0[it][2], a0[it][3]);
    v[2] = cvtpk(a1[it][0], a1[it][1]);
    v[3] = cvtpk(a1[it][2], a1[it][3]);
    *(u32x4*)(lds + it * 4096 + tid * 16) = v;
  }
}

// ---------------------------------------------------------------------------
// Expert tile (r13 structure + T14 A-prefetch): A issued during previous
// MFMA phase (L2 latency hidden; barrier 2 drains); B (w1t) via GLOAD16.
// ---------------------------------------------------------------------------
__device__ __forceinline__ void expert_tile(
    int e, int mbase, const float* __restrict__ z,
    const unsigned short* __restrict__ w1t, const float* __restrict__ b1,
    const float* __restrict__ w2, const float* __restrict__ b2,
    float* __restrict__ out, char* lds, int tid, int wq, int l15, int l4,
    int c8s) {
  char* ldsB = lds + 16384;
  const float* ag = z + (size_t)(mbase + (tid >> 3)) * 512 + c8s;
  const unsigned short* bg = w1t + e * 65536 + (tid >> 3) * 512 + c8s;
  const int wr = wq >> 1;  // row half of this wave
  const int wc = wq & 1;   // col half of this wave
  f32x4 pa0[4], pa1[4];
  load_A(ag, 0, pa0, pa1);  // prologue: A(0) in flight
  f32x4 acc[4][4] = {};
  for (int kt = 0; kt < 8; ++kt) {
    const int ko = kt * 64;
#pragma unroll
    for (int it = 0; it < 4; ++it)
      GLOAD16(bg + it * 32 * 512 + ko, ldsB + it * 4096 + tid * 16);
    write_A(lds, tid, pa0, pa1);  // cvt+store A(kt) (loads long since done)
    __syncthreads();
    if (kt < 7) load_A(ag, ko + 64, pa0, pa1);  // A(kt+1) flies under MFMAs
#pragma unroll
    for (int ks = 0; ks < 2; ++ks) {
      bf16x8 af[4];
#pragma unroll
      for (int rt = 0; rt < 4; ++rt)
        af[rt] = SWZ_FRAG(lds, wr * 64 + rt * 16 + l15, ks * 4 + l4);
#pragma unroll
      for (int ct = 0; ct < 4; ++ct) {
        bf16x8 bfv = SWZ_FRAG(ldsB, wc * 64 + ct * 16 + l15, ks * 4 + l4);
#pragma unroll
        for (int rt = 0; rt < 4; ++rt)
          acc[rt][ct] = __builtin_amdgcn_mfma_f32_16x16x32_bf16(
              af[rt], bfv, acc[rt][ct], 0, 0, 0);
      }
    }
    __syncthreads();
  }
  // epilogue: partial y over this wave's 64 cols, cross-wave combine
  float b1v[4], w2v[4];
#pragma unroll
  for (int ct = 0; ct < 4; ++ct) {
    int n = wc * 64 + ct * 16 + l15;
    b1v[ct] = b1[e * 128 + n];
    w2v[ct] = w2[e * 128 + n];
  }
  float* ylds = (float*)(lds + 32768);  // [4 waves][64 rows]
#pragma unroll
  for (int rt = 0; rt < 4; ++rt) {
#pragma unroll
    for (int i = 0; i < 4; ++i) {
      float s = 0.0f;
#pragma unroll
      for (int ct = 0; ct < 4; ++ct)
        s += gelu_s(acc[rt][ct][i] + b1v[ct]) * w2v[ct];
#pragma unroll
      for (int off = 1; off < 16; off <<= 1) s += __shfl_xor(s, off, 16);
      if (l15 == 0) ylds[wq * 64 + rt * 16 + l4 * 4 + i] = s;
    }
  }
  __syncthreads();
  if (tid < 128) {
    int rl = tid & 63, half = tid >> 6;
    float y = ylds[half * 128 + rl] + ylds[half * 128 + 64 + rl] + b2[e];
    out[(size_t)2097152 + (size_t)(mbase + half * 64 + rl) * 16 + e] = y;
  }
}

// ---------------------------------------------------------------------------
// Logits tile (r13 structure + same T14 A-prefetch). Wc from wct (L2-hot).
// ---------------------------------------------------------------------------
__device__ __forceinline__ void logits_tile(
    int mbase, const float* __restrict__ z,
    const unsigned short* __restrict__ wct, const float* __restrict__ bc,
    float* __restrict__ out, char* lds, int tid, int wq, int l15, int l4,
    int c8s) {
  const float* ag = z + (size_t)(mbase + (tid >> 3)) * 512 + c8s;
  const unsigned short* wb = wct + l15 * 512 + l4 * 8;  // direct, L2-hot
  f32x4 pa0[4], pa1[4];
  load_A(ag, 0, pa0, pa1);
  f32x4 acc2[2] = {};
  for (int kt = 0; kt < 8; ++kt) {
    const int ko = kt * 64;
    write_A(lds, tid, pa0, pa1);
    bf16x8 bfr0 = *(const bf16x8*)(wb + ko);
    bf16x8 bfr1 = *(const bf16x8*)(wb + ko + 32);
    __syncthreads();
    if (kt < 7) load_A(ag, ko + 64, pa0, pa1);
#pragma unroll
    for (int rt = 0; rt < 2; ++rt) {
      bf16x8 a0 = SWZ_FRAG(lds, wq * 32 + rt * 16 + l15, l4);
      acc2[rt] =
          __builtin_amdgcn_mfma_f32_16x16x32_bf16(a0, bfr0, acc2[rt], 0, 0, 0);
      bf16x8 a1 = SWZ_FRAG(lds, wq * 32 + rt * 16 + l15, 4 + l4);
      acc2[rt] =
          __builtin_amdgcn_mfma_f32_16x16x32_bf16(a1, bfr1, acc2[rt], 0, 0, 0);
    }
    __syncthreads();
  }
  float bcv = bc[l15];
#pragma unroll
  for (int rt = 0; rt < 2; ++rt) {
#pragma unroll
    for (int i = 0; i < 4; ++i) {
      int row = wq * 32 + rt * 16 + l4 * 4 + i;
      float lg = acc2[rt][i] + bcv;
      float mx = lg;
#pragma unroll
      for (int off = 1; off < 16; off <<= 1)
        mx = fmaxf(mx, __shfl_xor(mx, off, 16));
      float ex = __expf(lg - mx);
      float sm = ex;
#pragma unroll
      for (int off = 1; off < 16; off <<= 1) sm += __shfl_xor(sm, off, 16);
      size_t ro = (size_t)(mbase + row) * 16 + l15;
      out[ro] = lg;                 // logits
      out[1048576 + ro] = ex / sm;  // p_g
    }
  }
}

// ---------------------------------------------------------------------------
// Weight conversion (round-5 proven, ~8us).
// ---------------------------------------------------------------------------
__global__ __launch_bounds__(256) void k_convert(
    const float* __restrict__ W1, const float* __restrict__ Wc,
    unsigned short* __restrict__ w1t, unsigned short* __restrict__ wct) {
  int bid = blockIdx.x;
  int tid = threadIdx.x;
  if (bid < 1024) {
    __shared__ float tile[32][33];
    int gg = bid >> 6;
    int t = bid & 63;
    int d0 = (t >> 2) * 32;
    int h0 = (t & 3) * 32;
    int tx = tid & 31, ty = tid >> 5;
#pragma unroll
    for (int r = 0; r < 4; ++r)
      tile[r * 8 + ty][tx] = W1[(gg << 16) + (d0 + r * 8 + ty) * 128 + h0 + tx];
    __syncthreads();
#pragma unroll
    for (int r = 0; r < 4; ++r)
      w1t[(gg << 16) + (h0 + r * 8 + ty) * 512 + d0 + tx] =
          f2bf(tile[tx][r * 8 + ty]);
  } else {
#pragma unroll
    for (int j = 0; j < 32; ++j) {
      int i = j * 256 + tid;
      wct[(i & 15) * 512 + (i >> 4)] = f2bf(Wc[i]);
    }
  }
}

// ---------------------------------------------------------------------------
// Main kernel (r13 proven mapping, 8704 blocks):
//   xcd = bid&7, t = bid>>3, panel = xcd*64 + t/17, r = t%17.
// __launch_bounds__(256, 3): T14 prefetch keeps +32 VGPR live across the
// MFMA phase (~96 VGPR + 64 AGPR = 160); the (256,4) cap of 128 would spill
// (r14 lesson). 3 waves/EU -> 170-reg cap, 12 waves/CU.
// ---------------------------------------------------------------------------
__global__ __launch_bounds__(256, 3) void k_main(
    const float* __restrict__ z, const unsigned short* __restrict__ w1t,
    const unsigned short* __restrict__ wct, const float* __restrict__ bc,
    const float* __restrict__ b1, const float* __restrict__ w2,
    const float* __restrict__ b2, float* __restrict__ out) {
  __shared__ alignas(16) char lds[33792];
  const int tid = threadIdx.x;
  const int wq = tid >> 6;
  const int l15 = tid & 15;
  const int l4 = (tid >> 4) & 3;
  const int c8s = (((tid & 7) ^ ((tid >> 3) & 7))) * 8;
  const int xcd = blockIdx.x & 7;
  const int t = blockIdx.x >> 3;    // 0..1087
  const int pl = t / 17;            // panel-local 0..63
  const int r = t - pl * 17;        // 0..16
  const int mbase = (xcd * 64 + pl) * 128;
  if (r == 0)
    logits_tile(mbase, z, wct, bc, out, lds, tid, wq, l15, l4, c8s);
  else
    expert_tile(r - 1, mbase, z, w1t, b1, w2, b2, out, lds, tid, wq, l15, l4,
                c8s);
}

// ---------------------------------------------------------------------------
extern "C" void kernel_launch(void* const* d_in, const int* in_sizes, int n_in,
                              void* d_out, int out_size, void* d_ws,
                              size_t ws_size, hipStream_t stream) {
  const float* z = (const float*)d_in[0];
  const float* Wc = (const float*)d_in[1];
  const float* bc = (const float*)d_in[2];
  const float* W1 = (const float*)d_in[3];
  const float* b1 = (const float*)d_in[4];
  const float* W2 = (const float*)d_in[5];
  const float* b2 = (const float*)d_in[6];
  float* out = (float*)d_out;

  unsigned short* w1t = (unsigned short*)d_ws;           // 2 MB
  unsigned short* wct = w1t + (size_t)16 * 128 * 512;    // 16 KB

  k_convert<<<1024 + 1, 256, 0, stream>>>(W1, Wc, w1t, wct);
  k_main<<<8 * 1088, 256, 0, stream>>>(z, w1t, wct, bc, b1, W2, b2, out);
}